// Round 13
// baseline (464.195 us; speedup 1.0000x reference)
//
#include <hip/hip_runtime.h>
#include <math.h>

// ---------------- problem constants ----------------
constexpr int SEQ   = 2048;   // L
constexpr int HID   = 2048;
constexpr int NHQ   = 16;
constexpr int NHKV  = 4;
constexpr int GQ    = NHQ / NHKV;   // 4
constexpr int DH    = 128;
constexpr int CKS   = 32;     // compress window
constexpr int CKST  = 16;     // compress stride
constexpr int NCMP  = (SEQ - CKS) / CKST + 1;  // 127
constexpr int BSZ   = 64;     // selection block
constexpr int NTOP  = 16;
constexpr int NBLK  = SEQ / BSZ;   // 32
constexpr int MBB   = BSZ / CKST;  // 4
constexpr int WINW  = 512;
constexpr int CKD   = CKS * DH;    // 4096 = compress GEMM K
constexpr int NQKV  = HID + 2 * NHKV * DH;  // 3072 fused projection width
constexpr float SCALE = 0.08838834764831845f;  // 1/sqrt(128)
constexpr float NLN_10K_64 = 0.14391156514f;   // ln(10000)/64

typedef __attribute__((ext_vector_type(8))) short short8;     // 8 bf16 (4 VGPRs)
typedef __attribute__((ext_vector_type(4))) float f32x4;

static __device__ __forceinline__ unsigned short f2bf(float f) {
  unsigned u = __builtin_bit_cast(unsigned, f);
  u = (u + 0x7fffu + ((u >> 16) & 1u)) >> 16;
  return (unsigned short)u;
}
static __device__ __forceinline__ float bf2f(unsigned short u) {
  unsigned v = ((unsigned)u) << 16;
  return __builtin_bit_cast(float, v);
}
// async global->LDS 16B: lane i writes lds_base + i*16
static __device__ __forceinline__ void gload_lds16(const unsigned short* g, unsigned short* l) {
  __builtin_amdgcn_global_load_lds((const __attribute__((address_space(1))) unsigned int*)g,
                                   (__attribute__((address_space(3))) unsigned int*)l, 16, 0, 0);
}

// ======= merged PREP kernel: gate+xbf (1024 blk) | WqkvT (6144) | Wck/WcvT (4096) | WoT (4096) ====
__global__ __launch_bounds__(256) void prep_kernel(
    const float* __restrict__ x,  const float* __restrict__ Wg,
    const float* __restrict__ Wq, const float* __restrict__ Wk, const float* __restrict__ Wv,
    const float* __restrict__ Wo, const float* __restrict__ Wck, const float* __restrict__ Wcv,
    float* __restrict__ gate, unsigned short* __restrict__ xbf,
    unsigned short* __restrict__ WqkvT, unsigned short* __restrict__ WckT,
    unsigned short* __restrict__ WcvT, unsigned short* __restrict__ WoT) {
  __shared__ float tile[32][33];
  __shared__ float part[2][2][3];
  const int bx = blockIdx.x;
  const int t = threadIdx.x;
  if (bx < 1024) {
    // ---- gate = sigmoid(x @ Wg) + x -> bf16: 2 rows per block ----
    const int grp = t >> 7;
    const int i = bx * 2 + grp;
    const int tl = t & 127;
    const float* row = x + (size_t)i * HID;
    unsigned short* orow = xbf + (size_t)i * HID;
    float vals[16];
    {
      const float4* src = (const float4*)(row + tl * 16);
#pragma unroll
      for (int u = 0; u < 4; ++u) {
        const float4 v = src[u];
        vals[u * 4 + 0] = v.x; vals[u * 4 + 1] = v.y; vals[u * 4 + 2] = v.z; vals[u * 4 + 3] = v.w;
      }
    }
    float a0 = 0.f, a1 = 0.f, a2 = 0.f;
#pragma unroll
    for (int e = 0; e < 16; ++e) {
      const int kk = tl * 16 + e;
      a0 += vals[e] * Wg[kk * 3 + 0];
      a1 += vals[e] * Wg[kk * 3 + 1];
      a2 += vals[e] * Wg[kk * 3 + 2];
    }
    {
      short8 ob[2];
#pragma unroll
      for (int e = 0; e < 16; ++e) ((unsigned short*)ob)[e] = f2bf(vals[e]);
      *(short8*)(orow + tl * 16)     = ob[0];
      *(short8*)(orow + tl * 16 + 8) = ob[1];
    }
#pragma unroll
    for (int s = 1; s < 64; s <<= 1) {
      a0 += __shfl_xor(a0, s);
      a1 += __shfl_xor(a1, s);
      a2 += __shfl_xor(a2, s);
    }
    if ((tl & 63) == 0) {
      part[grp][tl >> 6][0] = a0; part[grp][tl >> 6][1] = a1; part[grp][tl >> 6][2] = a2;
    }
    __syncthreads();
    if (tl == 0) {
      gate[i * 3 + 0] = 1.f / (1.f + expf(-(part[grp][0][0] + part[grp][1][0])));
      gate[i * 3 + 1] = 1.f / (1.f + expf(-(part[grp][0][1] + part[grp][1][1])));
      gate[i * 3 + 2] = 1.f / (1.f + expf(-(part[grp][0][2] + part[grp][1][2])));
    }
    return;
  }
  // ---- f32 [K][N] -> bf16 [N][K] 32x32 tile transpose (job/coords block-uniform) ----
  const int b = bx - 1024;
  const int tx = t & 31, ty = t >> 5;   // 32 x 8
  const float* sp; unsigned short* dp; int sN; int dK;
  if (b < 6144) {                       // Wq/Wk/Wv -> WqkvT [3072][2048]
    const int nn = (b % 96) * 32, kk = (b / 96) * 32;
    int ncol;
    if (nn < HID)            { sp = Wq; ncol = nn;             sN = HID; }
    else if (nn < HID + 512) { sp = Wk; ncol = nn - HID;       sN = 512; }
    else                     { sp = Wv; ncol = nn - HID - 512; sN = 512; }
    sp += (size_t)kk * sN + ncol;
    dp = WqkvT + (size_t)nn * HID + kk; dK = HID;
  } else if (b < 10240) {               // Wck/Wcv [h][CKD][DH] -> [h][DH][CKD]
    const int b2 = b - 6144;
    const int nn = (b2 & 3) * 32, kk = ((b2 >> 2) & 127) * 32, z = b2 >> 9;
    sp = (z < 4 ? Wck : Wcv) + (size_t)(z & 3) * CKD * DH + (size_t)kk * DH + nn;
    sN = DH;
    dp = (z < 4 ? WckT : WcvT) + (size_t)(z & 3) * DH * CKD + (size_t)nn * CKD + kk; dK = CKD;
  } else {                              // Wo [2048][2048] -> WoT
    const int b3 = b - 10240;
    const int nn = (b3 & 63) * 32, kk = (b3 >> 6) * 32;
    sp = Wo + (size_t)kk * HID + nn; sN = HID;
    dp = WoT + (size_t)nn * (NHQ * DH) + kk; dK = NHQ * DH;
  }
#pragma unroll
  for (int r = 0; r < 4; ++r)
    tile[ty + 8 * r][tx] = sp[(size_t)(ty + 8 * r) * sN + tx];
  __syncthreads();
#pragma unroll
  for (int r = 0; r < 4; ++r)
    dp[(size_t)(ty + 8 * r) * dK + tx] = f2bf(tile[tx][ty + 8 * r]);
}

// ===== BM=64 x BN=128, BK=64 GEMM (plain f32 output): used for out projection =====
__global__ __launch_bounds__(256) void gemm_bf16_64(const unsigned short* __restrict__ A,
                                                    const unsigned short* __restrict__ Bt,
                                                    float* __restrict__ C,
                                                    int M, int N, int K) {
  __shared__ __align__(16) unsigned short As[2][64 * 64];    // 2 x 8 KB
  __shared__ __align__(16) unsigned short Bs[2][128 * 64];   // 2 x 16 KB
  const int t = threadIdx.x;
  const int w = t >> 6, lane = t & 63, col = lane & 15, quad = lane >> 4;
  const int gX = gridDim.x;
  const int nwg = gX * gridDim.y;
  const int lb = blockIdx.y * gX + blockIdx.x;
  const int sb = (lb & 7) * (nwg >> 3) + (lb >> 3);
  const int m0 = (sb / gX) * 64, n0 = (sb % gX) * 128;
  const int uA0 = (w * 2 + 0) * 64 + lane;
  const int uA1 = (w * 2 + 1) * 64 + lane;
  const int rA0 = uA0 >> 3, eA0 = (uA0 & 7) ^ (rA0 & 7);
  const int rA1 = uA1 >> 3, eA1 = (uA1 & 7) ^ (rA1 & 7);
  const unsigned short* gA0 = A + (size_t)(m0 + rA0) * K + eA0 * 8;
  const unsigned short* gA1 = A + (size_t)(m0 + rA1) * K + eA1 * 8;
  const unsigned short* gB[4];
#pragma unroll
  for (int j = 0; j < 4; ++j) {
    const int u = (w * 4 + j) * 64 + lane;
    const int rB = u >> 3, eB = (u & 7) ^ (rB & 7);
    gB[j] = Bt + (size_t)(n0 + rB) * K + eB * 8;
  }
  f32x4 acc[8];
#pragma unroll
  for (int ni = 0; ni < 8; ++ni) acc[ni] = f32x4{0.f, 0.f, 0.f, 0.f};

  const int S = K / 64;
  auto stage = [&](int s) {
    const int k0 = s * 64;
    const int b = s & 1;
    gload_lds16(gA0 + k0, &As[b][(w * 2 + 0) * 512]);
    gload_lds16(gA1 + k0, &As[b][(w * 2 + 1) * 512]);
#pragma unroll
    for (int j = 0; j < 4; ++j)
      gload_lds16(gB[j] + k0, &Bs[b][(w * 4 + j) * 512]);
  };
  stage(0);
  for (int s = 0; s < S; ++s) {
    __syncthreads();
    if (s + 1 < S) stage(s + 1);
    const unsigned short* as = As[s & 1];
    const unsigned short* bs = Bs[s & 1];
    const int rowA = w * 16 + col;
#pragma unroll
    for (int ks = 0; ks < 2; ++ks) {
      short8 af = *(const short8*)&as[rowA * 64 + ((((ks << 2) + quad) ^ (rowA & 7)) << 3)];
#pragma unroll
      for (int ni = 0; ni < 8; ++ni) {
        const int row = ni * 16 + col;
        short8 bfr = *(const short8*)&bs[row * 64 + ((((ks << 2) + quad) ^ (row & 7)) << 3)];
        acc[ni] = __builtin_amdgcn_mfma_f32_16x16x32_bf16(af, bfr, acc[ni], 0, 0, 0);
      }
    }
  }
#pragma unroll
  for (int ni = 0; ni < 8; ++ni)
#pragma unroll
    for (int r = 0; r < 4; ++r)
      C[(size_t)(m0 + w * 16 + quad * 4 + r) * N + n0 + ni * 16 + col] = acc[ni][r];
}

// ===== qkv projection GEMM with FUSED epilogue: RoPE(q,k) + V-transpose, no f32 qkv buffer =====
__global__ __launch_bounds__(256) void qkv_gemm_fused(const unsigned short* __restrict__ A,
                                                      const unsigned short* __restrict__ Bt,
                                                      unsigned short* __restrict__ qbf,
                                                      unsigned short* __restrict__ krbf,
                                                      float* __restrict__ knrf,
                                                      unsigned short* __restrict__ vbf,
                                                      unsigned short* __restrict__ vT) {
  __shared__ __align__(16) unsigned short sarena[24576];  // 48 KB arena (staging, then v-transpose)
  unsigned short* As0 = sarena;            // [2][64*64]  = 8192 shorts
  unsigned short* Bs0 = sarena + 8192;     // [2][128*64] = 16384 shorts
  const int t = threadIdx.x;
  const int w = t >> 6, lane = t & 63, col = lane & 15, quad = lane >> 4;
  constexpr int K = HID;
  const int gX = gridDim.x;                // 24
  const int nwg = gX * gridDim.y;          // 768 (%8==0)
  const int lb = blockIdx.y * gX + blockIdx.x;
  const int sb = (lb & 7) * (nwg >> 3) + (lb >> 3);
  const int m0 = (sb / gX) * 64, n0 = (sb % gX) * 128;
  const int uA0 = (w * 2 + 0) * 64 + lane;
  const int uA1 = (w * 2 + 1) * 64 + lane;
  const int rA0 = uA0 >> 3, eA0 = (uA0 & 7) ^ (rA0 & 7);
  const int rA1 = uA1 >> 3, eA1 = (uA1 & 7) ^ (rA1 & 7);
  const unsigned short* gA0 = A + (size_t)(m0 + rA0) * K + eA0 * 8;
  const unsigned short* gA1 = A + (size_t)(m0 + rA1) * K + eA1 * 8;
  const unsigned short* gB[4];
#pragma unroll
  for (int j = 0; j < 4; ++j) {
    const int u = (w * 4 + j) * 64 + lane;
    const int rB = u >> 3, eB = (u & 7) ^ (rB & 7);
    gB[j] = Bt + (size_t)(n0 + rB) * K + eB * 8;
  }
  f32x4 acc[8];
#pragma unroll
  for (int ni = 0; ni < 8; ++ni) acc[ni] = f32x4{0.f, 0.f, 0.f, 0.f};

  const int S = K / 64;
  auto stage = [&](int s) {
    const int k0 = s * 64;
    const int b = s & 1;
    gload_lds16(gA0 + k0, &As0[b * 4096 + (w * 2 + 0) * 512]);
    gload_lds16(gA1 + k0, &As0[b * 4096 + (w * 2 + 1) * 512]);
#pragma unroll
    for (int j = 0; j < 4; ++j)
      gload_lds16(gB[j] + k0, &Bs0[b * 8192 + (w * 4 + j) * 512]);
  };
  stage(0);
  for (int s = 0; s < S; ++s) {
    __syncthreads();
    if (s + 1 < S) stage(s + 1);
    const unsigned short* as = As0 + (s & 1) * 4096;
    const unsigned short* bs = Bs0 + (s & 1) * 8192;
    const int rowA = w * 16 + col;
#pragma unroll
    for (int ks = 0; ks < 2; ++ks) {
      short8 af = *(const short8*)&as[rowA * 64 + ((((ks << 2) + quad) ^ (rowA & 7)) << 3)];
#pragma unroll
      for (int ni = 0; ni < 8; ++ni) {
        const int row = ni * 16 + col;
        short8 bfr = *(const short8*)&bs[row * 64 + ((((ks << 2) + quad) ^ (row & 7)) << 3)];
        acc[ni] = __builtin_amdgcn_mfma_f32_16x16x32_bf16(af, bfr, acc[ni], 0, 0, 0);
      }
    }
  }

  // ---------------- fused epilogue (head index hd = n0/128, block-uniform) ----------------
  const int hd = n0 >> 7;            // 0..23: q 0-15, k 16-19, v 20-23
  const int rowb = w * 16 + quad * 4;
  if (hd < 20) {
    // RoPE: pair (d, d+64) = acc[ni], acc[ni+4]; angle = row * 10000^(-d/64)
    float invf[4];
#pragma unroll
    for (int ni = 0; ni < 4; ++ni) invf[ni] = __expf(-NLN_10K_64 * (float)(ni * 16 + col));
#pragma unroll
    for (int r = 0; r < 4; ++r) {
      const int row = m0 + rowb + r;
#pragma unroll
      for (int ni = 0; ni < 4; ++ni) {
        float c, s;
        sincosf((float)row * invf[ni], &s, &c);
        const float x1 = acc[ni][r], x2 = acc[ni + 4][r];
        const int d = ni * 16 + col;
        if (hd < 16) {
          unsigned short* q = qbf + ((size_t)row * NHQ + hd) * DH;
          q[d]      = f2bf(x1 * c - x2 * s);
          q[d + 64] = f2bf(x2 * c + x1 * s);
        } else {
          const int hk = hd - 16;
          unsigned short* kk = krbf + ((size_t)row * NHKV + hk) * DH;
          kk[d]      = f2bf(x1 * c - x2 * s);
          kk[d + 64] = f2bf(x2 * c + x1 * s);
          float* kn = knrf + ((size_t)row * NHKV + hk) * DH;
          kn[d] = x1;
          kn[d + 64] = x2;
        }
      }
    }
  } else {
    const int hv = hd - 20;
    // row-major bf16 vbf (bit-exact vs old f2bf(qkv_f32) path)
#pragma unroll
    for (int r = 0; r < 4; ++r) {
      const int row = m0 + rowb + r;
      unsigned short* vv = vbf + ((size_t)row * NHKV + hv) * DH;
#pragma unroll
      for (int ni = 0; ni < 8; ++ni) vv[ni * 16 + col] = f2bf(acc[ni][r]);
    }
    // LDS transpose -> vT[h][d][seq] with coalesced stores
    __syncthreads();                   // staging LDS now dead
    unsigned short* tl = sarena;       // [128][72] bf16 = 18 KB
#pragma unroll
    for (int r = 0; r < 4; ++r)
#pragma unroll
      for (int ni = 0; ni < 8; ++ni)
        tl[(ni * 16 + col) * 72 + rowb + r] = f2bf(acc[ni][r]);
    __syncthreads();
    {
      const int d = t >> 1, s0 = (t & 1) * 32;
      unsigned short* o = vT + ((size_t)(hv * DH + d)) * SEQ + m0 + s0;
#pragma unroll
      for (int e = 0; e < 32; e += 8)
        *(short8*)(o + e) = *(const short8*)&tl[d * 72 + s0 + e];
    }
  }
}

// ---------------- compress A-build from knrf/vbf: Ak/Av[h][128][4096] bf16 ----------------
__global__ __launch_bounds__(256) void abuild_kernel(const float* __restrict__ knrf,
                                                     const unsigned short* __restrict__ vbf,
                                                     const float* __restrict__ pe,
                                                     unsigned short* __restrict__ Ak,
                                                     unsigned short* __restrict__ Av) {
  const size_t u = (size_t)blockIdx.x * 256 + threadIdx.x;  // < 4*128*4096
  const int h = (int)(u >> 19);
  const int rem = (int)(u & 524287);
  const int n = rem >> 12;
  const int e = rem & 4095;
  const int s = e >> 7;
  const int d = e & 127;
  int row = n * CKST + s; if (row > SEQ - 1) row = SEQ - 1;  // pad row (n=127 unused)
  const size_t o = ((size_t)row * NHKV + h) * DH + d;
  Ak[u] = f2bf(knrf[o] + pe[((size_t)h * CKS + s) * DH + d]);
  Av[u] = vbf[o];
}

// ---------------- compress GEMM: split-K 16 chunks, z = mat*64 + h*16 + kc, glds staging ---------
__global__ __launch_bounds__(256) void compress_gemm(const unsigned short* __restrict__ Ak,
                                                     const unsigned short* __restrict__ Av,
                                                     const unsigned short* __restrict__ WckT,
                                                     const unsigned short* __restrict__ WcvT,
                                                     float* __restrict__ Cpart) {
  __shared__ __align__(16) unsigned short As[2][128 * 32];
  __shared__ __align__(16) unsigned short Bs[2][128 * 32];
  const int z = blockIdx.x;
  const int mat = z >> 6;
  const int h = (z >> 4) & 3;
  const int kc = z & 15;
  const unsigned short* A  = (mat ? Av : Ak)     + (size_t)h * 128 * CKD;
  const unsigned short* Bt = (mat ? WcvT : WckT) + (size_t)h * DH * CKD;
  float* Cout = Cpart + (size_t)z * 128 * 128;
  const int t = threadIdx.x;
  const int w = t >> 6, lane = t & 63, col = lane & 15, quad = lane >> 4;
  const int uA0 = (w * 2 + 0) * 64 + lane;
  const int uA1 = (w * 2 + 1) * 64 + lane;
  const int r0 = uA0 >> 2, e0 = (uA0 & 3) ^ ((r0 >> 1) & 3);
  const int r1 = uA1 >> 2, e1 = (uA1 & 3) ^ ((r1 >> 1) & 3);
  const int kbase = kc * 256;
  const unsigned short* gA0 = A + (size_t)r0 * CKD + kbase + e0 * 8;
  const unsigned short* gA1 = A + (size_t)r1 * CKD + kbase + e1 * 8;
  const unsigned short* gB0 = Bt + (size_t)r0 * CKD + kbase + e0 * 8;
  const unsigned short* gB1 = Bt + (size_t)r1 * CKD + kbase + e1 * 8;
  f32x4 acc[2][8];
#pragma unroll
  for (int mi = 0; mi < 2; ++mi)
#pragma unroll
    for (int ni = 0; ni < 8; ++ni) acc[mi][ni] = f32x4{0.f, 0.f, 0.f, 0.f};
  auto stage = [&](int s) {
    const int k0 = s * 32;
    const int b = s & 1;
    gload_lds16(gA0 + k0, &As[b][(w * 2 + 0) * 512]);
    gload_lds16(gA1 + k0, &As[b][(w * 2 + 1) * 512]);
    gload_lds16(gB0 + k0, &Bs[b][(w * 2 + 0) * 512]);
    gload_lds16(gB1 + k0, &Bs[b][(w * 2 + 1) * 512]);
  };
  stage(0);
  for (int s = 0; s < 8; ++s) {
    __syncthreads();
    if (s + 1 < 8) stage(s + 1);
    const unsigned short* as = As[s & 1];
    const unsigned short* bs = Bs[s & 1];
    short8 af[2], bfr[8];
#pragma unroll
    for (int mi = 0; mi < 2; ++mi) {
      const int row = w * 32 + mi * 16 + col;
      af[mi] = *(const short8*)&as[(row * 4 + (quad ^ ((row >> 1) & 3))) * 8];
    }
#pragma unroll
    for (int ni = 0; ni < 8; ++ni) {
      const int row = ni * 16 + col;
      bfr[ni] = *(const short8*)&bs[(row * 4 + (quad ^ ((row >> 1) & 3))) * 8];
    }
#pragma unroll
    for (int mi = 0; mi < 2; ++mi)
#pragma unroll
      for (int ni = 0; ni < 8; ++ni)
        acc[mi][ni] = __builtin_amdgcn_mfma_f32_16x16x32_bf16(af[mi], bfr[ni], acc[mi][ni], 0, 0, 0);
  }
#pragma unroll
  for (int mi = 0; mi < 2; ++mi)
#pragma unroll
    for (int ni = 0; ni < 8; ++ni)
#pragma unroll
      for (int r = 0; r < 4; ++r)
        Cout[(size_t)(w * 32 + mi * 16 + quad * 4 + r) * 128 + ni * 16 + col] = acc[mi][ni][r];
}

// -------- compress reduce (16 chunks) + fused ck-RoPE -> ckbf ; cv -> TRANSPOSED cvT[h][d][n] -----
__global__ __launch_bounds__(256) void compress_reduce_rope(const float* __restrict__ Cpart,
                                                            unsigned short* __restrict__ ckbf,
                                                            unsigned short* __restrict__ cvT) {
  const unsigned u = blockIdx.x * 256 + threadIdx.x;  // < 32768 + 65536
  if (u < 32768) {  // ck with rope: (h, n, d<64)
    const int h = u >> 13;
    const int rem = u & 8191;
    const int n = rem >> 6;
    const int d = rem & 63;
    const size_t b0 = ((size_t)(h * 16) << 14) + n * 128 + d;
    float x1 = 0.f, x2 = 0.f;
#pragma unroll
    for (int kc = 0; kc < 16; ++kc) {
      x1 += Cpart[b0 + (size_t)kc * 16384];
      x2 += Cpart[b0 + 64 + (size_t)kc * 16384];
    }
    const float inv = __expf(-NLN_10K_64 * (float)d);
    const float ang = (float)(n * CKST) * inv;
    float c, s;
    sincosf(ang, &s, &c);
    const size_t o = ((size_t)n * NHKV + h) * DH + d;
    ckbf[o]      = f2bf(x1 * c - x2 * s);
    ckbf[o + 64] = f2bf(x2 * c + x1 * s);
  } else {  // cv: (h, n, d) -> cvT[h][d][n] (n=127 zeroed: only 127 real compressed blocks)
    const unsigned u2 = u - 32768;
    const int h = u2 >> 14;
    const int rem = u2 & 16383;
    const size_t b0 = ((size_t)(64 + h * 16) << 14) + rem;
    float s = 0.f;
#pragma unroll
    for (int kc = 0; kc < 16; ++kc) s += Cpart[b0 + (size_t)kc * 16384];
    const int n = rem >> 7, d = rem & 127;
    cvT[((size_t)h * DH + d) * 128 + n] = (n == 127) ? (unsigned short)0 : f2bf(s);
  }
}

// ======= FUSED compressed attention + top-k + selected/window attention + combine =======
// V operands (cvT phase 1, vT phase 2) are read DIRECTLY from global (L2-resident, 16B-contiguous
// MFMA B-fragments) -> LDS arena shrinks 78KB -> 43KB -> 3 blocks/CU on a latency-bound kernel.
constexpr int CSTR = 136;
__global__ __launch_bounds__(256, 3) void fused_attn_kernel(
    const unsigned short* __restrict__ qbf,
    const unsigned short* __restrict__ ckbf,
    const unsigned short* __restrict__ cvT,
    const unsigned short* __restrict__ kbf,
    const unsigned short* __restrict__ vT,
    const float* __restrict__ gate,
    unsigned short* __restrict__ outc) {
  __shared__ __align__(16) unsigned char smem[43328];
  // phase-1 aliases
  unsigned short* cks  = (unsigned short*)(smem);              // 64*136*2   = 17408
  unsigned short* PsC  = (unsigned short*)(smem + 17408);      // 4*16*136*2 = 17408
  float (*pscore)[132] = (float (*)[132])(smem + 34816);       // 16*132*4   = 8448
  unsigned* smask_l    = (unsigned*)(smem + 43264);            // 16*4       = 64 (survives phase 2)
  // phase-2 aliases (overlap phase-1 buffers; all crossings barrier-separated)
  unsigned short* Ks   = (unsigned short*)(smem);              // [2][64*128] = 32768
  unsigned short* PsN  = (unsigned short*)(smem + 32768);      // [4][16*64]  = 8192 -> 40960

  const int bx = blockIdx.x;
  const int qt = 127 - (bx >> 2);   // big-work blocks first
  const int h = bx & 3;
  const int i0 = qt * 16;
  const int t = threadIdx.x;
  const int w = t >> 6;
  const int lane = t & 63;
  const int col = lane & 15;
  const int quad = lane >> 4;
  const int i_lane = i0 + 4 * w + quad;   // == iq of cmp phase

  short8 qf[4];
  {
    const int qi = i0 + 4 * w + (col >> 2);
    const int g = col & 3;
    const unsigned short* qp = qbf + ((size_t)qi * NHQ + h * GQ + g) * DH + quad * 8;
#pragma unroll
    for (int dc = 0; dc < 4; ++dc) qf[dc] = *(const short8*)(qp + dc * 32);
  }

  // phase-2 K staging helper (tile 0 prefetched during top-k); V is direct-global
  auto stageK = [&](int b, int kb) {
#pragma unroll
    for (int qq = 0; qq < 4; ++qq) {
      const int q = w * 4 + qq;
      const int u = q * 64 + lane;
      const int r = u >> 4;
      const int c = (u & 15) ^ (r & 7);
      const unsigned short* g = kbf + ((size_t)((b * 64 + r) * NHKV + h)) * DH + c * 8;
      gload_lds16(g, &Ks[kb * 8192 + q * 512]);
    }
  };

  // ================= phase 1: compressed attention =================
  if (t < 64) pscore[t >> 2][128 + (t & 3)] = 0.f;
  const int jmax = (i_lane >= CKS - 1) ? ((i_lane - (CKS - 1)) >> 4) : -1;

  float sreg[8][4];
  for (int ch = 0; ch < 2; ++ch) {
    if (ch) __syncthreads();
    {
      const int r = t >> 2, c0 = (t & 3) * 32;
      const unsigned short* src = ckbf + ((size_t)(ch * 64 + r) * NHKV + h) * DH + c0;
#pragma unroll
      for (int u = 0; u < 4; ++u)
        *(short8*)&cks[r * CSTR + c0 + u * 8] = *(const short8*)(src + u * 8);
    }
    __syncthreads();
#pragma unroll
    for (int tt = 0; tt < 4; ++tt) {
      f32x4 s = f32x4{0.f, 0.f, 0.f, 0.f};
#pragma unroll
      for (int dc = 0; dc < 4; ++dc)
        s = __builtin_amdgcn_mfma_f32_16x16x32_bf16(
            qf[dc], *(const short8*)&cks[(tt * 16 + col) * CSTR + dc * 32 + quad * 8], s, 0, 0, 0);
#pragma unroll
      for (int r = 0; r < 4; ++r) sreg[ch * 4 + tt][r] = s[r];
    }
  }

#pragma unroll
  for (int r = 0; r < 4; ++r) {
    float l = 0.f;
#pragma unroll
    for (int tt = 0; tt < 8; ++tt) {
      const float p = (tt * 16 + col <= jmax) ? __expf(sreg[tt][r] * SCALE) : 0.f;
      sreg[tt][r] = p;
      l += p;
    }
    l += __shfl_xor(l, 1); l += __shfl_xor(l, 2); l += __shfl_xor(l, 4); l += __shfl_xor(l, 8);
    const float rden = 1.f / fmaxf(l, 1e-20f);
#pragma unroll
    for (int tt = 0; tt < 8; ++tt) {
      const float pn = sreg[tt][r] * rden;
      sreg[tt][r] = pn;
      PsC[w * 2176 + (quad * 4 + r) * CSTR + tt * 16 + col] = f2bf(pn);
    }
  }
#pragma unroll
  for (int tt = 0; tt < 8; ++tt)
    pscore[4 * w + quad][tt * 16 + col] = sreg[tt][0] + sreg[tt][1] + sreg[tt][2] + sreg[tt][3];

  // barrier: PsC writes visible to all waves (each wave reads only its own PsC slice; keep order)
  f32x4 accCmp[8];
#pragma unroll
  for (int dt = 0; dt < 8; ++dt) accCmp[dt] = f32x4{0.f, 0.f, 0.f, 0.f};
#pragma unroll
  for (int kt = 0; kt < 4; ++kt) {
    short8 ap = *(const short8*)&PsC[w * 2176 + col * CSTR + kt * 32 + quad * 8];
#pragma unroll
    for (int dt = 0; dt < 8; ++dt) {
      // V B-fragment direct from transposed global cvT[h][d][n] (L2-resident)
      short8 vf = *(const short8*)&cvT[((size_t)h * DH + dt * 16 + col) * 128 + kt * 32 + quad * 8];
      accCmp[dt] = __builtin_amdgcn_mfma_f32_16x16x32_bf16(ap, vf, accCmp[dt], 0, 0, 0);
    }
  }

  __syncthreads();   // all waves done with cks/PsC -> Ks region reusable
  // prefetch phase-2 tile 0 (block 0 force-selected); latency hides under the top-k
  stageK(0, 0);
  // ---- lane-parallel top-k -> smask_l; forced blocks {0, qblk-1, qblk} pre-inserted ----
  {
    const int j32 = lane & 31;
#pragma unroll
    for (int pass = 0; pass < 2; ++pass) {
      const int row = pass * 8 + w * 2 + (lane >> 5);
      const int i = i0 + row;
      const int qblk = i >> 6;
      float sc = pscore[row][j32 * 4 + 0] + 2.f * pscore[row][j32 * 4 + 1]
               + 2.f * pscore[row][j32 * 4 + 2] + 2.f * pscore[row][j32 * 4 + 3]
               + pscore[row][j32 * 4 + 4];
      const bool causal = (j32 <= qblk);
      const bool forced = (j32 < 1) || ((j32 > qblk - 2) && causal);
      float val = (causal && !forced) ? sc : -INFINITY;
      unsigned msk;
      int nf;
      if (qblk >= 2) { msk = 1u | (3u << (qblk - 1)); nf = 3; }
      else           { msk = (1u << (qblk + 1)) - 1u; nf = qblk + 1; }
      for (int it = 0; it < NTOP - nf; ++it) {
        float mx = val;
        mx = fmaxf(mx, __shfl_xor(mx, 1));
        mx = fmaxf(mx, __shfl_xor(mx, 2));
        mx = fmaxf(mx, __shfl_xor(mx, 4));
        mx = fmaxf(mx, __shfl_xor(mx, 8));
        mx = fmaxf(mx, __shfl_xor(mx, 16));
        if (mx == -INFINITY) break;
        const unsigned long long bal = __ballot(val == mx);
        const unsigned grp = (lane >= 32) ? (unsigned)(bal >> 32) : (unsigned)bal;
        const int first = __builtin_ctz(grp);
        msk |= (1u << first);
        if (j32 == first) val = -INFINITY;
      }
      if (j32 == 0) smask_l[row] = msk;
    }
  }
  __syncthreads();

  // ================= phase 2: selected + window attention =================
  const unsigned mymask = smask_l[4 * w + quad];
  unsigned bmask;
  {
    unsigned mm = smask_l[col];
    mm |= __shfl_xor(mm, 1); mm |= __shfl_xor(mm, 2);
    mm |= __shfl_xor(mm, 4); mm |= __shfl_xor(mm, 8);
    const int whi = (i0 + 15) >> 6;
    int wl = i0 - WINW; wl = (wl < 0) ? 0 : (wl >> 6);
    const unsigned hib = (whi >= 31) ? ~0u : ((1u << (whi + 1)) - 1u);
    bmask = (mm | (hib & ~((1u << wl) - 1u))) & hib;
  }
  const int i0w = i0 + w * 4;

  f32x4 accS[8], accW[8], accC[8];
#pragma unroll
  for (int dt = 0; dt < 8; ++dt) {
    accS[dt] = f32x4{0.f,0.f,0.f,0.f};
    accW[dt] = f32x4{0.f,0.f,0.f,0.f};
    accC[dt] = f32x4{0.f,0.f,0.f,0.f};
  }
  float lS[4], lW[4], lC[4];
#pragma unroll
  for (int r = 0; r < 4; ++r) { lS[r] = 0.f; lW[r] = 0.f; lC[r] = 0.f; }

  unsigned tmw = bmask;
  int cur = (int)__builtin_ctz(tmw);   // always 0 (block 0 forced); tile 0 already staged
  tmw &= tmw - 1;
  int buf = 0;
  while (cur >= 0) {
    int nxt = -1;
    if (tmw) { nxt = (int)__builtin_ctz(tmw); tmw &= tmw - 1; }
    __syncthreads();                 // buf staged; prev compute (on buf^1) done
    if (nxt >= 0) stageK(nxt, buf ^ 1);

    const int j0 = cur * 64;
    const bool wact = (j0 <= i0w + 3);
    const bool selbit = wact && ((mymask >> cur) & 1u);
    const bool selAny = (__ballot(selbit) != 0ull);
    const bool winAny = wact && (j0 + 63 >= i0w - WINW);
    const bool winFull = (j0 >= i0w + 3 - WINW);
    const bool common = winFull && __all(selbit);

    if (selAny || winAny) {
      f32x4 sc[4];
#pragma unroll
      for (int kt = 0; kt < 4; ++kt) {
        f32x4 ss = f32x4{0.f, 0.f, 0.f, 0.f};
        const int row = kt * 16 + col;
#pragma unroll
        for (int dc = 0; dc < 4; ++dc) {
          short8 kf = *(const short8*)&Ks[buf * 8192 + row * 128 + (((dc * 4 + quad) ^ (row & 7)) << 3)];
          ss = __builtin_amdgcn_mfma_f32_16x16x32_bf16(qf[dc], kf, ss, 0, 0, 0);
        }
        sc[kt] = ss;
      }
#pragma unroll
      for (int kt = 0; kt < 4; ++kt)
#pragma unroll
        for (int r = 0; r < 4; ++r)
          sc[kt][r] = __expf(sc[kt][r] * SCALE);

      const int jA = j0 + col, jB = jA + 16, jC = jA + 32, jD = jA + 48;

      auto do_pass = [&](int mode, float* lrun, f32x4* acc) {
#pragma unroll
        for (int r = 0; r < 4; ++r) {
          const bool a0 = (jA <= i_lane) && (mode == 0 ? selbit : (mode == 1 ? (jA >= i_lane - WINW) : true));
          const bool a1 = (jB <= i_lane) && (mode == 0 ? selbit : (mode == 1 ? (jB >= i_lane - WINW) : true));
          const bool a2 = (jC <= i_lane) && (mode == 0 ? selbit : (mode == 1 ? (jC >= i_lane - WINW) : true));
          const bool a3 = (jD <= i_lane) && (mode == 0 ? selbit : (mode == 1 ? (jD >= i_lane - WINW) : true));
          const float p0 = a0 ? sc[0][r] : 0.f;
          const float p1 = a1 ? sc[1][r] : 0.f;
          const float p2 = a2 ? sc[2][r] : 0.f;
          const float p3 = a3 ? sc[3][r] : 0.f;
          lrun[r] += p0 + p1 + p2 + p3;
          const int m = quad * 4 + r;
          const int cl = col & 7, ch = col >> 3;
          PsN[w * 1024 + m * 64 + (((0 + ch) ^ (m & 7)) << 3) + cl] = f2bf(p0);
          PsN[w * 1024 + m * 64 + (((2 + ch) ^ (m & 7)) << 3) + cl] = f2bf(p1);
          PsN[w * 1024 + m * 64 + (((4 + ch) ^ (m & 7)) << 3) + cl] = f2bf(p2);
          PsN[w * 1024 + m * 64 + (((6 + ch) ^ (m & 7)) << 3) + cl] = f2bf(p3);
        }
        short8 ap0 = *(const short8*)&PsN[w * 1024 + col * 64 + (((0 + quad) ^ (col & 7)) << 3)];
        short8 ap1 = *(const short8*)&PsN[w * 1024 + col * 64 + (((4 + quad) ^ (col & 7)) << 3)];
#pragma unroll
        for (int dt = 0; dt < 8; ++dt) {
          const int rv = dt * 16 + col;
          // V fragments direct from global vT (L2-resident; loads hoist above use)
          const unsigned short* vp = vT + ((size_t)(h * DH + rv)) * SEQ + j0 + quad * 8;
          acc[dt] = __builtin_amdgcn_mfma_f32_16x16x32_bf16(ap0, *(const short8*)vp, acc[dt], 0, 0, 0);
          acc[dt] = __builtin_amdgcn_mfma_f32_16x16x32_bf16(ap1, *(const short8*)(vp + 32), acc[dt], 0, 0, 0);
        }
      };

      if (common) {
        do_pass(2, lC, accC);
      } else {
        if (selAny) do_pass(0, lS, accS);
        if (winAny) do_pass(1, lW, accW);
      }
    }
    cur = nxt;
    buf ^= 1;
  }

  // epilogue: merge common stream; cmp contribution straight from registers (f32, no bf16 bounce)
#pragma unroll
  for (int r = 0; r < 4; ++r) {
    float a = lS[r] + lC[r];
    a += __shfl_xor(a, 1); a += __shfl_xor(a, 2); a += __shfl_xor(a, 4); a += __shfl_xor(a, 8);
    lS[r] = a;
    float b = lW[r] + lC[r];
    b += __shfl_xor(b, 1); b += __shfl_xor(b, 2); b += __shfl_xor(b, 4); b += __shfl_xor(b, 8);
    lW[r] = b;
  }
  const float g0 = gate[i_lane * 3 + 0];
  const float g1 = gate[i_lane * 3 + 1];
  const float g2 = gate[i_lane * 3 + 2];
#pragma unroll
  for (int r = 0; r < 4; ++r) {
    const size_t base = ((size_t)i_lane * NHQ + h * 4 + r) * DH;
    const float rls = g1 / lS[r];
    const float rlw = g2 / lW[r];
#pragma unroll
    for (int dt = 0; dt < 8; ++dt) {
      const size_t o = base + dt * 16 + col;
      outc[o] = f2bf(g0 * accCmp[dt][r] + rls * (accS[dt][r] + accC[dt][r])
                                        + rlw * (accW[dt][r] + accC[dt][r]));
    }
  }
}

// ---------------- launcher ----------------
extern "C" void kernel_launch(void* const* d_in, const int* in_sizes, int n_in,
                              void* d_out, int out_size, void* d_ws, size_t ws_size,
                              hipStream_t stream) {
  const float* x   = (const float*)d_in[0];
  const float* Wq  = (const float*)d_in[2];
  const float* Wk  = (const float*)d_in[3];
  const float* Wv  = (const float*)d_in[4];
  const float* Wo  = (const float*)d_in[5];
  const float* Wck = (const float*)d_in[6];
  const float* Wcv = (const float*)d_in[7];
  const float* pe  = (const float*)d_in[8];
  const float* Wg  = (const float*)d_in[9];
  float* out = (float*)d_out;

  unsigned char* p = (unsigned char*)d_ws;
  auto alloc = [&](size_t bytes) { void* r = p; p += (bytes + 255) & ~(size_t)255; return r; };
  float* gbuf = (float*)alloc((size_t)SEQ * 4 * 4);
  unsigned short* ckbf = (unsigned short*)alloc((size_t)128 * NHKV * DH * 2);
  unsigned short* cvT  = (unsigned short*)alloc((size_t)NHKV * DH * 128 * 2);  // transposed cv
  unsigned short* xbf  = (unsigned short*)alloc((size_t)SEQ * HID * 2);        // 8MB; -> Ak/Av
  unsigned short* WqkvT = (unsigned short*)alloc((size_t)NQKV * HID * 2);      // 12MB; -> Cpart -> combbf
  unsigned short* WckT = (unsigned short*)alloc((size_t)NHKV * DH * CKD * 2);  // 4MB
  unsigned short* WcvT = (unsigned short*)alloc((size_t)NHKV * DH * CKD * 2);  // 4MB
  unsigned short* qbf  = (unsigned short*)alloc((size_t)SEQ * NHQ * DH * 2);   // 8MB
  unsigned short* krbf = (unsigned short*)alloc((size_t)SEQ * NHKV * DH * 2);  // 2MB
  float*          knrf = (float*)alloc((size_t)SEQ * NHKV * DH * 4);           // 4MB (raw k f32)
  unsigned short* vbf  = (unsigned short*)alloc((size_t)SEQ * NHKV * DH * 2);  // 2MB
  unsigned short* vT   = (unsigned short*)alloc((size_t)NHKV * DH * SEQ * 2);  // 2MB
  unsigned short* WoT  = (unsigned short*)alloc((size_t)NHQ * DH * HID * 2);   // 8MB (dedicated)
  unsigned short* Ak     = xbf;                                   // overlay xbf (dead after qkv GEMM)
  unsigned short* Av     = xbf + (size_t)NHKV * 128 * CKD;
  float* Cpart = (float*)WqkvT;                                   // 8MB overlay (weights dead after GEMM)
  unsigned short* combbf = WqkvT;                                 // overlay after Cpart dead

  // merged prep: gate+x->bf16 | Wq/Wk/Wv transpose | Wck/Wcv transpose | Wo transpose
  prep_kernel<<<15360, 256, 0, stream>>>(x, Wg, Wq, Wk, Wv, Wo, Wck, Wcv,
                                         gbuf, xbf, WqkvT, WckT, WcvT, WoT);
  // qkv projection with fused RoPE/V-transpose epilogue (no f32 qkv intermediate)
  qkv_gemm_fused<<<dim3(NQKV / 128, SEQ / 64), 256, 0, stream>>>(xbf, WqkvT, qbf, krbf, knrf, vbf, vT);
  // compression as GEMM (A-build over dead xbf; Cpart overlays dead WqkvT weights)
  abuild_kernel<<<(NHKV * 128 * CKD) / 256, 256, 0, stream>>>(knrf, vbf, pe, Ak, Av);
  compress_gemm<<<128, 256, 0, stream>>>(Ak, Av, WckT, WcvT, Cpart);
  compress_reduce_rope<<<(32768 + 65536) / 256, 256, 0, stream>>>(Cpart, ckbf, cvT);
  // fused compressed-attn + top-k + selected/window attn + gated combine (43KB LDS, 3 blocks/CU)
  fused_attn_kernel<<<(SEQ / 16) * NHKV, 256, 0, stream>>>(qbf, ckbf, cvT, krbf, vT, gbuf, combbf);
  // output projection (BM=64, BK=64 tile: 512 blocks = 2 blocks/CU)
  gemm_bf16_64<<<dim3(HID / 128, SEQ / 64), 256, 0, stream>>>(combbf, WoT, out, SEQ, HID, NHQ * DH);
}

// Round 14
// 290.130 us; speedup vs baseline: 1.6000x; 1.6000x over previous
//
#include <hip/hip_runtime.h>
#include <math.h>

// ---------------- problem constants ----------------
constexpr int SEQ   = 2048;   // L
constexpr int HID   = 2048;
constexpr int NHQ   = 16;
constexpr int NHKV  = 4;
constexpr int GQ    = NHQ / NHKV;   // 4
constexpr int DH    = 128;
constexpr int CKS   = 32;     // compress window
constexpr int CKST  = 16;     // compress stride
constexpr int NCMP  = (SEQ - CKS) / CKST + 1;  // 127
constexpr int BSZ   = 64;     // selection block
constexpr int NTOP  = 16;
constexpr int NBLK  = SEQ / BSZ;   // 32
constexpr int MBB   = BSZ / CKST;  // 4
constexpr int WINW  = 512;
constexpr int CKD   = CKS * DH;    // 4096 = compress GEMM K
constexpr int NQKV  = HID + 2 * NHKV * DH;  // 3072 fused projection width
constexpr float SCALE = 0.08838834764831845f;  // 1/sqrt(128)
constexpr float NLN_10K_64 = 0.14391156514f;   // ln(10000)/64

typedef __attribute__((ext_vector_type(8))) short short8;     // 8 bf16 (4 VGPRs)
typedef __attribute__((ext_vector_type(4))) float f32x4;

static __device__ __forceinline__ unsigned short f2bf(float f) {
  unsigned u = __builtin_bit_cast(unsigned, f);
  u = (u + 0x7fffu + ((u >> 16) & 1u)) >> 16;
  return (unsigned short)u;
}
static __device__ __forceinline__ float bf2f(unsigned short u) {
  unsigned v = ((unsigned)u) << 16;
  return __builtin_bit_cast(float, v);
}
// async global->LDS 16B: lane i writes lds_base + i*16
static __device__ __forceinline__ void gload_lds16(const unsigned short* g, unsigned short* l) {
  __builtin_amdgcn_global_load_lds((const __attribute__((address_space(1))) unsigned int*)g,
                                   (__attribute__((address_space(3))) unsigned int*)l, 16, 0, 0);
}

// ======= merged PREP kernel: gate+xbf (1024 blk) | WqkvT (6144) | Wck/WcvT (4096) | WoT (4096) ====
__global__ __launch_bounds__(256) void prep_kernel(
    const float* __restrict__ x,  const float* __restrict__ Wg,
    const float* __restrict__ Wq, const float* __restrict__ Wk, const float* __restrict__ Wv,
    const float* __restrict__ Wo, const float* __restrict__ Wck, const float* __restrict__ Wcv,
    float* __restrict__ gate, unsigned short* __restrict__ xbf,
    unsigned short* __restrict__ WqkvT, unsigned short* __restrict__ WckT,
    unsigned short* __restrict__ WcvT, unsigned short* __restrict__ WoT) {
  __shared__ float tile[32][33];
  __shared__ float part[2][2][3];
  const int bx = blockIdx.x;
  const int t = threadIdx.x;
  if (bx < 1024) {
    // ---- gate = sigmoid(x @ Wg) + x -> bf16: 2 rows per block ----
    const int grp = t >> 7;
    const int i = bx * 2 + grp;
    const int tl = t & 127;
    const float* row = x + (size_t)i * HID;
    unsigned short* orow = xbf + (size_t)i * HID;
    float vals[16];
    {
      const float4* src = (const float4*)(row + tl * 16);
#pragma unroll
      for (int u = 0; u < 4; ++u) {
        const float4 v = src[u];
        vals[u * 4 + 0] = v.x; vals[u * 4 + 1] = v.y; vals[u * 4 + 2] = v.z; vals[u * 4 + 3] = v.w;
      }
    }
    float a0 = 0.f, a1 = 0.f, a2 = 0.f;
#pragma unroll
    for (int e = 0; e < 16; ++e) {
      const int kk = tl * 16 + e;
      a0 += vals[e] * Wg[kk * 3 + 0];
      a1 += vals[e] * Wg[kk * 3 + 1];
      a2 += vals[e] * Wg[kk * 3 + 2];
    }
    {
      short8 ob[2];
#pragma unroll
      for (int e = 0; e < 16; ++e) ((unsigned short*)ob)[e] = f2bf(vals[e]);
      *(short8*)(orow + tl * 16)     = ob[0];
      *(short8*)(orow + tl * 16 + 8) = ob[1];
    }
#pragma unroll
    for (int s = 1; s < 64; s <<= 1) {
      a0 += __shfl_xor(a0, s);
      a1 += __shfl_xor(a1, s);
      a2 += __shfl_xor(a2, s);
    }
    if ((tl & 63) == 0) {
      part[grp][tl >> 6][0] = a0; part[grp][tl >> 6][1] = a1; part[grp][tl >> 6][2] = a2;
    }
    __syncthreads();
    if (tl == 0) {
      gate[i * 3 + 0] = 1.f / (1.f + expf(-(part[grp][0][0] + part[grp][1][0])));
      gate[i * 3 + 1] = 1.f / (1.f + expf(-(part[grp][0][1] + part[grp][1][1])));
      gate[i * 3 + 2] = 1.f / (1.f + expf(-(part[grp][0][2] + part[grp][1][2])));
    }
    return;
  }
  // ---- f32 [K][N] -> bf16 [N][K] 32x32 tile transpose (job/coords block-uniform) ----
  const int b = bx - 1024;
  const int tx = t & 31, ty = t >> 5;   // 32 x 8
  const float* sp; unsigned short* dp; int sN; int dK;
  if (b < 6144) {                       // Wq/Wk/Wv -> WqkvT [3072][2048]
    const int nn = (b % 96) * 32, kk = (b / 96) * 32;
    int ncol;
    if (nn < HID)            { sp = Wq; ncol = nn;             sN = HID; }
    else if (nn < HID + 512) { sp = Wk; ncol = nn - HID;       sN = 512; }
    else                     { sp = Wv; ncol = nn - HID - 512; sN = 512; }
    sp += (size_t)kk * sN + ncol;
    dp = WqkvT + (size_t)nn * HID + kk; dK = HID;
  } else if (b < 10240) {               // Wck/Wcv [h][CKD][DH] -> [h][DH][CKD]
    const int b2 = b - 6144;
    const int nn = (b2 & 3) * 32, kk = ((b2 >> 2) & 127) * 32, z = b2 >> 9;
    sp = (z < 4 ? Wck : Wcv) + (size_t)(z & 3) * CKD * DH + (size_t)kk * DH + nn;
    sN = DH;
    dp = (z < 4 ? WckT : WcvT) + (size_t)(z & 3) * DH * CKD + (size_t)nn * CKD + kk; dK = CKD;
  } else {                              // Wo [2048][2048] -> WoT
    const int b3 = b - 10240;
    const int nn = (b3 & 63) * 32, kk = (b3 >> 6) * 32;
    sp = Wo + (size_t)kk * HID + nn; sN = HID;
    dp = WoT + (size_t)nn * (NHQ * DH) + kk; dK = NHQ * DH;
  }
#pragma unroll
  for (int r = 0; r < 4; ++r)
    tile[ty + 8 * r][tx] = sp[(size_t)(ty + 8 * r) * sN + tx];
  __syncthreads();
#pragma unroll
  for (int r = 0; r < 4; ++r)
    dp[(size_t)(ty + 8 * r) * dK + tx] = f2bf(tile[tx][ty + 8 * r]);
}

// ===== BM=64 x BN=128, BK=64 GEMM (plain f32 output): used for out projection =====
__global__ __launch_bounds__(256) void gemm_bf16_64(const unsigned short* __restrict__ A,
                                                    const unsigned short* __restrict__ Bt,
                                                    float* __restrict__ C,
                                                    int M, int N, int K) {
  __shared__ __align__(16) unsigned short As[2][64 * 64];    // 2 x 8 KB
  __shared__ __align__(16) unsigned short Bs[2][128 * 64];   // 2 x 16 KB
  const int t = threadIdx.x;
  const int w = t >> 6, lane = t & 63, col = lane & 15, quad = lane >> 4;
  const int gX = gridDim.x;
  const int nwg = gX * gridDim.y;
  const int lb = blockIdx.y * gX + blockIdx.x;
  const int sb = (lb & 7) * (nwg >> 3) + (lb >> 3);
  const int m0 = (sb / gX) * 64, n0 = (sb % gX) * 128;
  const int uA0 = (w * 2 + 0) * 64 + lane;
  const int uA1 = (w * 2 + 1) * 64 + lane;
  const int rA0 = uA0 >> 3, eA0 = (uA0 & 7) ^ (rA0 & 7);
  const int rA1 = uA1 >> 3, eA1 = (uA1 & 7) ^ (rA1 & 7);
  const unsigned short* gA0 = A + (size_t)(m0 + rA0) * K + eA0 * 8;
  const unsigned short* gA1 = A + (size_t)(m0 + rA1) * K + eA1 * 8;
  const unsigned short* gB[4];
#pragma unroll
  for (int j = 0; j < 4; ++j) {
    const int u = (w * 4 + j) * 64 + lane;
    const int rB = u >> 3, eB = (u & 7) ^ (rB & 7);
    gB[j] = Bt + (size_t)(n0 + rB) * K + eB * 8;
  }
  f32x4 acc[8];
#pragma unroll
  for (int ni = 0; ni < 8; ++ni) acc[ni] = f32x4{0.f, 0.f, 0.f, 0.f};

  const int S = K / 64;
  auto stage = [&](int s) {
    const int k0 = s * 64;
    const int b = s & 1;
    gload_lds16(gA0 + k0, &As[b][(w * 2 + 0) * 512]);
    gload_lds16(gA1 + k0, &As[b][(w * 2 + 1) * 512]);
#pragma unroll
    for (int j = 0; j < 4; ++j)
      gload_lds16(gB[j] + k0, &Bs[b][(w * 4 + j) * 512]);
  };
  stage(0);
  for (int s = 0; s < S; ++s) {
    __syncthreads();
    if (s + 1 < S) stage(s + 1);
    const unsigned short* as = As[s & 1];
    const unsigned short* bs = Bs[s & 1];
    const int rowA = w * 16 + col;
#pragma unroll
    for (int ks = 0; ks < 2; ++ks) {
      short8 af = *(const short8*)&as[rowA * 64 + ((((ks << 2) + quad) ^ (rowA & 7)) << 3)];
#pragma unroll
      for (int ni = 0; ni < 8; ++ni) {
        const int row = ni * 16 + col;
        short8 bfr = *(const short8*)&bs[row * 64 + ((((ks << 2) + quad) ^ (row & 7)) << 3)];
        acc[ni] = __builtin_amdgcn_mfma_f32_16x16x32_bf16(af, bfr, acc[ni], 0, 0, 0);
      }
    }
  }
#pragma unroll
  for (int ni = 0; ni < 8; ++ni)
#pragma unroll
    for (int r = 0; r < 4; ++r)
      C[(size_t)(m0 + w * 16 + quad * 4 + r) * N + n0 + ni * 16 + col] = acc[ni][r];
}

// ===== qkv projection GEMM with FUSED epilogue: RoPE(q,k) + V-transpose, no f32 qkv buffer =====
__global__ __launch_bounds__(256) void qkv_gemm_fused(const unsigned short* __restrict__ A,
                                                      const unsigned short* __restrict__ Bt,
                                                      unsigned short* __restrict__ qbf,
                                                      unsigned short* __restrict__ krbf,
                                                      float* __restrict__ knrf,
                                                      unsigned short* __restrict__ vbf,
                                                      unsigned short* __restrict__ vT) {
  __shared__ __align__(16) unsigned short sarena[24576];  // 48 KB arena (staging, then v-transpose)
  unsigned short* As0 = sarena;            // [2][64*64]  = 8192 shorts
  unsigned short* Bs0 = sarena + 8192;     // [2][128*64] = 16384 shorts
  const int t = threadIdx.x;
  const int w = t >> 6, lane = t & 63, col = lane & 15, quad = lane >> 4;
  constexpr int K = HID;
  const int gX = gridDim.x;                // 24
  const int nwg = gX * gridDim.y;          // 768 (%8==0)
  const int lb = blockIdx.y * gX + blockIdx.x;
  const int sb = (lb & 7) * (nwg >> 3) + (lb >> 3);
  const int m0 = (sb / gX) * 64, n0 = (sb % gX) * 128;
  const int uA0 = (w * 2 + 0) * 64 + lane;
  const int uA1 = (w * 2 + 1) * 64 + lane;
  const int rA0 = uA0 >> 3, eA0 = (uA0 & 7) ^ (rA0 & 7);
  const int rA1 = uA1 >> 3, eA1 = (uA1 & 7) ^ (rA1 & 7);
  const unsigned short* gA0 = A + (size_t)(m0 + rA0) * K + eA0 * 8;
  const unsigned short* gA1 = A + (size_t)(m0 + rA1) * K + eA1 * 8;
  const unsigned short* gB[4];
#pragma unroll
  for (int j = 0; j < 4; ++j) {
    const int u = (w * 4 + j) * 64 + lane;
    const int rB = u >> 3, eB = (u & 7) ^ (rB & 7);
    gB[j] = Bt + (size_t)(n0 + rB) * K + eB * 8;
  }
  f32x4 acc[8];
#pragma unroll
  for (int ni = 0; ni < 8; ++ni) acc[ni] = f32x4{0.f, 0.f, 0.f, 0.f};

  const int S = K / 64;
  auto stage = [&](int s) {
    const int k0 = s * 64;
    const int b = s & 1;
    gload_lds16(gA0 + k0, &As0[b * 4096 + (w * 2 + 0) * 512]);
    gload_lds16(gA1 + k0, &As0[b * 4096 + (w * 2 + 1) * 512]);
#pragma unroll
    for (int j = 0; j < 4; ++j)
      gload_lds16(gB[j] + k0, &Bs0[b * 8192 + (w * 4 + j) * 512]);
  };
  stage(0);
  for (int s = 0; s < S; ++s) {
    __syncthreads();
    if (s + 1 < S) stage(s + 1);
    const unsigned short* as = As0 + (s & 1) * 4096;
    const unsigned short* bs = Bs0 + (s & 1) * 8192;
    const int rowA = w * 16 + col;
#pragma unroll
    for (int ks = 0; ks < 2; ++ks) {
      short8 af = *(const short8*)&as[rowA * 64 + ((((ks << 2) + quad) ^ (rowA & 7)) << 3)];
#pragma unroll
      for (int ni = 0; ni < 8; ++ni) {
        const int row = ni * 16 + col;
        short8 bfr = *(const short8*)&bs[row * 64 + ((((ks << 2) + quad) ^ (row & 7)) << 3)];
        acc[ni] = __builtin_amdgcn_mfma_f32_16x16x32_bf16(af, bfr, acc[ni], 0, 0, 0);
      }
    }
  }

  // ---------------- fused epilogue (head index hd = n0/128, block-uniform) ----------------
  const int hd = n0 >> 7;            // 0..23: q 0-15, k 16-19, v 20-23
  const int rowb = w * 16 + quad * 4;
  if (hd < 20) {
    // RoPE: pair (d, d+64) = acc[ni], acc[ni+4]; angle = row * 10000^(-d/64)
    float invf[4];
#pragma unroll
    for (int ni = 0; ni < 4; ++ni) invf[ni] = __expf(-NLN_10K_64 * (float)(ni * 16 + col));
#pragma unroll
    for (int r = 0; r < 4; ++r) {
      const int row = m0 + rowb + r;
#pragma unroll
      for (int ni = 0; ni < 4; ++ni) {
        float c, s;
        sincosf((float)row * invf[ni], &s, &c);
        const float x1 = acc[ni][r], x2 = acc[ni + 4][r];
        const int d = ni * 16 + col;
        if (hd < 16) {
          unsigned short* q = qbf + ((size_t)row * NHQ + hd) * DH;
          q[d]      = f2bf(x1 * c - x2 * s);
          q[d + 64] = f2bf(x2 * c + x1 * s);
        } else {
          const int hk = hd - 16;
          unsigned short* kk = krbf + ((size_t)row * NHKV + hk) * DH;
          kk[d]      = f2bf(x1 * c - x2 * s);
          kk[d + 64] = f2bf(x2 * c + x1 * s);
          float* kn = knrf + ((size_t)row * NHKV + hk) * DH;
          kn[d] = x1;
          kn[d + 64] = x2;
        }
      }
    }
  } else {
    const int hv = hd - 20;
    // row-major bf16 vbf (bit-exact vs old f2bf(qkv_f32) path)
#pragma unroll
    for (int r = 0; r < 4; ++r) {
      const int row = m0 + rowb + r;
      unsigned short* vv = vbf + ((size_t)row * NHKV + hv) * DH;
#pragma unroll
      for (int ni = 0; ni < 8; ++ni) vv[ni * 16 + col] = f2bf(acc[ni][r]);
    }
    // LDS transpose -> vT[h][d][seq] with coalesced stores
    __syncthreads();                   // staging LDS now dead
    unsigned short* tl = sarena;       // [128][72] bf16 = 18 KB
#pragma unroll
    for (int r = 0; r < 4; ++r)
#pragma unroll
      for (int ni = 0; ni < 8; ++ni)
        tl[(ni * 16 + col) * 72 + rowb + r] = f2bf(acc[ni][r]);
    __syncthreads();
    {
      const int d = t >> 1, s0 = (t & 1) * 32;
      unsigned short* o = vT + ((size_t)(hv * DH + d)) * SEQ + m0 + s0;
#pragma unroll
      for (int e = 0; e < 32; e += 8)
        *(short8*)(o + e) = *(const short8*)&tl[d * 72 + s0 + e];
    }
  }
}

// ---------------- compress A-build from knrf/vbf: Ak/Av[h][128][4096] bf16 ----------------
__global__ __launch_bounds__(256) void abuild_kernel(const float* __restrict__ knrf,
                                                     const unsigned short* __restrict__ vbf,
                                                     const float* __restrict__ pe,
                                                     unsigned short* __restrict__ Ak,
                                                     unsigned short* __restrict__ Av) {
  const size_t u = (size_t)blockIdx.x * 256 + threadIdx.x;  // < 4*128*4096
  const int h = (int)(u >> 19);
  const int rem = (int)(u & 524287);
  const int n = rem >> 12;
  const int e = rem & 4095;
  const int s = e >> 7;
  const int d = e & 127;
  int row = n * CKST + s; if (row > SEQ - 1) row = SEQ - 1;  // pad row (n=127 unused)
  const size_t o = ((size_t)row * NHKV + h) * DH + d;
  Ak[u] = f2bf(knrf[o] + pe[((size_t)h * CKS + s) * DH + d]);
  Av[u] = vbf[o];
}

// ---------------- compress GEMM: split-K 16 chunks, z = mat*64 + h*16 + kc, glds staging ---------
__global__ __launch_bounds__(256) void compress_gemm(const unsigned short* __restrict__ Ak,
                                                     const unsigned short* __restrict__ Av,
                                                     const unsigned short* __restrict__ WckT,
                                                     const unsigned short* __restrict__ WcvT,
                                                     float* __restrict__ Cpart) {
  __shared__ __align__(16) unsigned short As[2][128 * 32];
  __shared__ __align__(16) unsigned short Bs[2][128 * 32];
  const int z = blockIdx.x;
  const int mat = z >> 6;
  const int h = (z >> 4) & 3;
  const int kc = z & 15;
  const unsigned short* A  = (mat ? Av : Ak)     + (size_t)h * 128 * CKD;
  const unsigned short* Bt = (mat ? WcvT : WckT) + (size_t)h * DH * CKD;
  float* Cout = Cpart + (size_t)z * 128 * 128;
  const int t = threadIdx.x;
  const int w = t >> 6, lane = t & 63, col = lane & 15, quad = lane >> 4;
  const int uA0 = (w * 2 + 0) * 64 + lane;
  const int uA1 = (w * 2 + 1) * 64 + lane;
  const int r0 = uA0 >> 2, e0 = (uA0 & 3) ^ ((r0 >> 1) & 3);
  const int r1 = uA1 >> 2, e1 = (uA1 & 3) ^ ((r1 >> 1) & 3);
  const int kbase = kc * 256;
  const unsigned short* gA0 = A + (size_t)r0 * CKD + kbase + e0 * 8;
  const unsigned short* gA1 = A + (size_t)r1 * CKD + kbase + e1 * 8;
  const unsigned short* gB0 = Bt + (size_t)r0 * CKD + kbase + e0 * 8;
  const unsigned short* gB1 = Bt + (size_t)r1 * CKD + kbase + e1 * 8;
  f32x4 acc[2][8];
#pragma unroll
  for (int mi = 0; mi < 2; ++mi)
#pragma unroll
    for (int ni = 0; ni < 8; ++ni) acc[mi][ni] = f32x4{0.f, 0.f, 0.f, 0.f};
  auto stage = [&](int s) {
    const int k0 = s * 32;
    const int b = s & 1;
    gload_lds16(gA0 + k0, &As[b][(w * 2 + 0) * 512]);
    gload_lds16(gA1 + k0, &As[b][(w * 2 + 1) * 512]);
    gload_lds16(gB0 + k0, &Bs[b][(w * 2 + 0) * 512]);
    gload_lds16(gB1 + k0, &Bs[b][(w * 2 + 1) * 512]);
  };
  stage(0);
  for (int s = 0; s < 8; ++s) {
    __syncthreads();
    if (s + 1 < 8) stage(s + 1);
    const unsigned short* as = As[s & 1];
    const unsigned short* bs = Bs[s & 1];
    short8 af[2], bfr[8];
#pragma unroll
    for (int mi = 0; mi < 2; ++mi) {
      const int row = w * 32 + mi * 16 + col;
      af[mi] = *(const short8*)&as[(row * 4 + (quad ^ ((row >> 1) & 3))) * 8];
    }
#pragma unroll
    for (int ni = 0; ni < 8; ++ni) {
      const int row = ni * 16 + col;
      bfr[ni] = *(const short8*)&bs[(row * 4 + (quad ^ ((row >> 1) & 3))) * 8];
    }
#pragma unroll
    for (int mi = 0; mi < 2; ++mi)
#pragma unroll
      for (int ni = 0; ni < 8; ++ni)
        acc[mi][ni] = __builtin_amdgcn_mfma_f32_16x16x32_bf16(af[mi], bfr[ni], acc[mi][ni], 0, 0, 0);
  }
#pragma unroll
  for (int mi = 0; mi < 2; ++mi)
#pragma unroll
    for (int ni = 0; ni < 8; ++ni)
#pragma unroll
      for (int r = 0; r < 4; ++r)
        Cout[(size_t)(w * 32 + mi * 16 + quad * 4 + r) * 128 + ni * 16 + col] = acc[mi][ni][r];
}

// ---------------- compress reduce (16 chunks) + fused ck-RoPE -> ckbf / cvbf ----------------
__global__ __launch_bounds__(256) void compress_reduce_rope(const float* __restrict__ Cpart,
                                                            unsigned short* __restrict__ ckbf,
                                                            unsigned short* __restrict__ cvbf) {
  const unsigned u = blockIdx.x * 256 + threadIdx.x;  // < 32768 + 65536
  if (u < 32768) {  // ck with rope: (h, n, d<64)
    const int h = u >> 13;
    const int rem = u & 8191;
    const int n = rem >> 6;
    const int d = rem & 63;
    const size_t b0 = ((size_t)(h * 16) << 14) + n * 128 + d;
    float x1 = 0.f, x2 = 0.f;
#pragma unroll
    for (int kc = 0; kc < 16; ++kc) {
      x1 += Cpart[b0 + (size_t)kc * 16384];
      x2 += Cpart[b0 + 64 + (size_t)kc * 16384];
    }
    const float inv = __expf(-NLN_10K_64 * (float)d);
    const float ang = (float)(n * CKST) * inv;
    float c, s;
    sincosf(ang, &s, &c);
    const size_t o = ((size_t)n * NHKV + h) * DH + d;
    ckbf[o]      = f2bf(x1 * c - x2 * s);
    ckbf[o + 64] = f2bf(x2 * c + x1 * s);
  } else {  // cv: (h, n, d)
    const unsigned u2 = u - 32768;
    const int h = u2 >> 14;
    const int rem = u2 & 16383;
    const size_t b0 = ((size_t)(64 + h * 16) << 14) + rem;
    float s = 0.f;
#pragma unroll
    for (int kc = 0; kc < 16; ++kc) s += Cpart[b0 + (size_t)kc * 16384];
    const int n = rem >> 7, d = rem & 127;
    cvbf[((size_t)n * NHKV + h) * DH + d] = f2bf(s);
  }
}

// ======= FUSED compressed attention + top-k + selected/window attention + combine =======
constexpr int CSTR = 136;
__global__ __launch_bounds__(256, 2) void fused_attn_kernel(
    const unsigned short* __restrict__ qbf,
    const unsigned short* __restrict__ ckbf,
    const unsigned short* __restrict__ cvbf,
    const unsigned short* __restrict__ kbf,
    const unsigned short* __restrict__ vT,
    const float* __restrict__ gate,
    unsigned short* __restrict__ outc) {
  __shared__ __align__(16) unsigned char smem[78144];
  // phase-1 aliases
  unsigned short* cks  = (unsigned short*)(smem);              // 64*136*2   = 17408
  unsigned short* cvts = (unsigned short*)(smem + 17408);      // 128*136*2  = 34816
  unsigned short* PsC  = (unsigned short*)(smem + 52224);      // 4*16*136*2 = 17408
  float (*pscore)[132] = (float (*)[132])(smem + 69632);       // 16*132*4   = 8448
  unsigned* smask_l    = (unsigned*)(smem + 78080);            // 16*4       = 64 (survives phase 2)
  // phase-2 aliases (overlap phase-1 buffers; all crossings barrier-separated)
  unsigned short* Ks   = (unsigned short*)(smem);              // [2][64*128] = 32768
  unsigned short* Vs   = (unsigned short*)(smem + 32768);      // [2][128*64] = 32768
  unsigned short* PsN  = (unsigned short*)(smem + 65536);      // [4][16*64]  = 8192 -> 73728

  const int bx = blockIdx.x;
  const int qt = 127 - (bx >> 2);   // big-work blocks first
  const int h = bx & 3;
  const int i0 = qt * 16;
  const int t = threadIdx.x;
  const int w = t >> 6;
  const int lane = t & 63;
  const int col = lane & 15;
  const int quad = lane >> 4;
  const int i_lane = i0 + 4 * w + quad;   // == iq of cmp phase

  short8 qf[4];
  {
    const int qi = i0 + 4 * w + (col >> 2);
    const int g = col & 3;
    const unsigned short* qp = qbf + ((size_t)qi * NHQ + h * GQ + g) * DH + quad * 8;
#pragma unroll
    for (int dc = 0; dc < 4; ++dc) qf[dc] = *(const short8*)(qp + dc * 32);
  }

  // phase-2 staging helpers (tile 0 prefetched during top-k)
  auto stageK = [&](int b, int kb) {
#pragma unroll
    for (int qq = 0; qq < 4; ++qq) {
      const int q = w * 4 + qq;
      const int u = q * 64 + lane;
      const int r = u >> 4;
      const int c = (u & 15) ^ (r & 7);
      const unsigned short* g = kbf + ((size_t)((b * 64 + r) * NHKV + h)) * DH + c * 8;
      gload_lds16(g, &Ks[kb * 8192 + q * 512]);
    }
  };
  auto stageV = [&](int b, int kb) {
#pragma unroll
    for (int qq = 0; qq < 4; ++qq) {
      const int q = w * 4 + qq;
      const int u = q * 64 + lane;
      const int d = u >> 3;
      const int c = (u & 7) ^ (d & 7);
      const unsigned short* g = vT + ((size_t)(h * DH + d)) * SEQ + b * 64 + c * 8;
      gload_lds16(g, &Vs[kb * 8192 + q * 512]);
    }
  };

  // ================= phase 1: compressed attention =================
  if (t < 64) pscore[t >> 2][128 + (t & 3)] = 0.f;
  const int jmax = (i_lane >= CKS - 1) ? ((i_lane - (CKS - 1)) >> 4) : -1;

  float sreg[8][4];
  for (int ch = 0; ch < 2; ++ch) {
    if (ch) __syncthreads();
    {
      const int r = t >> 2, c0 = (t & 3) * 32;
      const unsigned short* src = ckbf + ((size_t)(ch * 64 + r) * NHKV + h) * DH + c0;
#pragma unroll
      for (int u = 0; u < 4; ++u)
        *(short8*)&cks[r * CSTR + c0 + u * 8] = *(const short8*)(src + u * 8);
    }
    if (ch == 0) {
      const int j = t >> 1, d0 = (t & 1) * 64;
      const unsigned short* vsrc = cvbf + ((size_t)j * NHKV + h) * DH + d0;
#pragma unroll
      for (int u = 0; u < 16; ++u) {
        if (j == 127) {
#pragma unroll
          for (int dd = 0; dd < 4; ++dd) cvts[(d0 + u * 4 + dd) * CSTR + j] = 0;
        } else {
          const unsigned short* vv = vsrc + u * 4;
#pragma unroll
          for (int dd = 0; dd < 4; ++dd) cvts[(d0 + u * 4 + dd) * CSTR + j] = vv[dd];
        }
      }
    }
    __syncthreads();
#pragma unroll
    for (int tt = 0; tt < 4; ++tt) {
      f32x4 s = f32x4{0.f, 0.f, 0.f, 0.f};
#pragma unroll
      for (int dc = 0; dc < 4; ++dc)
        s = __builtin_amdgcn_mfma_f32_16x16x32_bf16(
            qf[dc], *(const short8*)&cks[(tt * 16 + col) * CSTR + dc * 32 + quad * 8], s, 0, 0, 0);
#pragma unroll
      for (int r = 0; r < 4; ++r) sreg[ch * 4 + tt][r] = s[r];
    }
  }

#pragma unroll
  for (int r = 0; r < 4; ++r) {
    float l = 0.f;
#pragma unroll
    for (int tt = 0; tt < 8; ++tt) {
      const float p = (tt * 16 + col <= jmax) ? __expf(sreg[tt][r] * SCALE) : 0.f;
      sreg[tt][r] = p;
      l += p;
    }
    l += __shfl_xor(l, 1); l += __shfl_xor(l, 2); l += __shfl_xor(l, 4); l += __shfl_xor(l, 8);
    const float rden = 1.f / fmaxf(l, 1e-20f);
#pragma unroll
    for (int tt = 0; tt < 8; ++tt) {
      const float pn = sreg[tt][r] * rden;
      sreg[tt][r] = pn;
      PsC[w * 2176 + (quad * 4 + r) * CSTR + tt * 16 + col] = f2bf(pn);
    }
  }
#pragma unroll
  for (int tt = 0; tt < 8; ++tt)
    pscore[4 * w + quad][tt * 16 + col] = sreg[tt][0] + sreg[tt][1] + sreg[tt][2] + sreg[tt][3];

  f32x4 accCmp[8];
#pragma unroll
  for (int dt = 0; dt < 8; ++dt) accCmp[dt] = f32x4{0.f, 0.f, 0.f, 0.f};
#pragma unroll
  for (int kt = 0; kt < 4; ++kt) {
    short8 ap = *(const short8*)&PsC[w * 2176 + col * CSTR + kt * 32 + quad * 8];
#pragma unroll
    for (int dt = 0; dt < 8; ++dt)
      accCmp[dt] = __builtin_amdgcn_mfma_f32_16x16x32_bf16(
          ap, *(const short8*)&cvts[(dt * 16 + col) * CSTR + kt * 32 + quad * 8], accCmp[dt], 0, 0, 0);
  }

  __syncthreads();   // all waves done with cks/cvts/PsC -> Ks/Vs region reusable
  // prefetch phase-2 tile 0 (block 0 force-selected); latency hides under the top-k
  stageK(0, 0);
  stageV(0, 0);
  // ---- lane-parallel top-k -> smask_l; forced blocks {0, qblk-1, qblk} pre-inserted ----
  {
    const int j32 = lane & 31;
#pragma unroll
    for (int pass = 0; pass < 2; ++pass) {
      const int row = pass * 8 + w * 2 + (lane >> 5);
      const int i = i0 + row;
      const int qblk = i >> 6;
      float sc = pscore[row][j32 * 4 + 0] + 2.f * pscore[row][j32 * 4 + 1]
               + 2.f * pscore[row][j32 * 4 + 2] + 2.f * pscore[row][j32 * 4 + 3]
               + pscore[row][j32 * 4 + 4];
      const bool causal = (j32 <= qblk);
      const bool forced = (j32 < 1) || ((j32 > qblk - 2) && causal);
      float val = (causal && !forced) ? sc : -INFINITY;
      unsigned msk;
      int nf;
      if (qblk >= 2) { msk = 1u | (3u << (qblk - 1)); nf = 3; }
      else           { msk = (1u << (qblk + 1)) - 1u; nf = qblk + 1; }
      for (int it = 0; it < NTOP - nf; ++it) {
        float mx = val;
        mx = fmaxf(mx, __shfl_xor(mx, 1));
        mx = fmaxf(mx, __shfl_xor(mx, 2));
        mx = fmaxf(mx, __shfl_xor(mx, 4));
        mx = fmaxf(mx, __shfl_xor(mx, 8));
        mx = fmaxf(mx, __shfl_xor(mx, 16));
        if (mx == -INFINITY) break;
        const unsigned long long bal = __ballot(val == mx);
        const unsigned grp = (lane >= 32) ? (unsigned)(bal >> 32) : (unsigned)bal;
        const int first = __builtin_ctz(grp);
        msk |= (1u << first);
        if (j32 == first) val = -INFINITY;
      }
      if (j32 == 0) smask_l[row] = msk;
    }
  }
  __syncthreads();

  // ================= phase 2: selected + window attention =================
  const unsigned mymask = smask_l[4 * w + quad];
  unsigned bmask;
  {
    unsigned mm = smask_l[col];
    mm |= __shfl_xor(mm, 1); mm |= __shfl_xor(mm, 2);
    mm |= __shfl_xor(mm, 4); mm |= __shfl_xor(mm, 8);
    const int whi = (i0 + 15) >> 6;
    int wl = i0 - WINW; wl = (wl < 0) ? 0 : (wl >> 6);
    const unsigned hib = (whi >= 31) ? ~0u : ((1u << (whi + 1)) - 1u);
    bmask = (mm | (hib & ~((1u << wl) - 1u))) & hib;
  }
  const int i0w = i0 + w * 4;

  f32x4 accS[8], accW[8], accC[8];
#pragma unroll
  for (int dt = 0; dt < 8; ++dt) {
    accS[dt] = f32x4{0.f,0.f,0.f,0.f};
    accW[dt] = f32x4{0.f,0.f,0.f,0.f};
    accC[dt] = f32x4{0.f,0.f,0.f,0.f};
  }
  float lS[4], lW[4], lC[4];
#pragma unroll
  for (int r = 0; r < 4; ++r) { lS[r] = 0.f; lW[r] = 0.f; lC[r] = 0.f; }

  unsigned tmw = bmask;
  int cur = (int)__builtin_ctz(tmw);   // always 0 (block 0 forced); tile 0 already staged
  tmw &= tmw - 1;
  int buf = 0;
  while (cur >= 0) {
    int nxt = -1;
    if (tmw) { nxt = (int)__builtin_ctz(tmw); tmw &= tmw - 1; }
    __syncthreads();                 // buf staged; prev compute (on buf^1) done
    if (nxt >= 0) { stageK(nxt, buf ^ 1); stageV(nxt, buf ^ 1); }

    const int j0 = cur * 64;
    const bool wact = (j0 <= i0w + 3);
    const bool selbit = wact && ((mymask >> cur) & 1u);
    const bool selAny = (__ballot(selbit) != 0ull);
    const bool winAny = wact && (j0 + 63 >= i0w - WINW);
    const bool winFull = (j0 >= i0w + 3 - WINW);
    const bool common = winFull && __all(selbit);

    if (selAny || winAny) {
      f32x4 sc[4];
#pragma unroll
      for (int kt = 0; kt < 4; ++kt) {
        f32x4 ss = f32x4{0.f, 0.f, 0.f, 0.f};
        const int row = kt * 16 + col;
#pragma unroll
        for (int dc = 0; dc < 4; ++dc) {
          short8 kf = *(const short8*)&Ks[buf * 8192 + row * 128 + (((dc * 4 + quad) ^ (row & 7)) << 3)];
          ss = __builtin_amdgcn_mfma_f32_16x16x32_bf16(qf[dc], kf, ss, 0, 0, 0);
        }
        sc[kt] = ss;
      }
#pragma unroll
      for (int kt = 0; kt < 4; ++kt)
#pragma unroll
        for (int r = 0; r < 4; ++r)
          sc[kt][r] = __expf(sc[kt][r] * SCALE);

      const int jA = j0 + col, jB = jA + 16, jC = jA + 32, jD = jA + 48;

      auto do_pass = [&](int mode, float* lrun, f32x4* acc) {
#pragma unroll
        for (int r = 0; r < 4; ++r) {
          const bool a0 = (jA <= i_lane) && (mode == 0 ? selbit : (mode == 1 ? (jA >= i_lane - WINW) : true));
          const bool a1 = (jB <= i_lane) && (mode == 0 ? selbit : (mode == 1 ? (jB >= i_lane - WINW) : true));
          const bool a2 = (jC <= i_lane) && (mode == 0 ? selbit : (mode == 1 ? (jC >= i_lane - WINW) : true));
          const bool a3 = (jD <= i_lane) && (mode == 0 ? selbit : (mode == 1 ? (jD >= i_lane - WINW) : true));
          const float p0 = a0 ? sc[0][r] : 0.f;
          const float p1 = a1 ? sc[1][r] : 0.f;
          const float p2 = a2 ? sc[2][r] : 0.f;
          const float p3 = a3 ? sc[3][r] : 0.f;
          lrun[r] += p0 + p1 + p2 + p3;
          const int m = quad * 4 + r;
          const int cl = col & 7, ch = col >> 3;
          PsN[w * 1024 + m * 64 + (((0 + ch) ^ (m & 7)) << 3) + cl] = f2bf(p0);
          PsN[w * 1024 + m * 64 + (((2 + ch) ^ (m & 7)) << 3) + cl] = f2bf(p1);
          PsN[w * 1024 + m * 64 + (((4 + ch) ^ (m & 7)) << 3) + cl] = f2bf(p2);
          PsN[w * 1024 + m * 64 + (((6 + ch) ^ (m & 7)) << 3) + cl] = f2bf(p3);
        }
        short8 ap0 = *(const short8*)&PsN[w * 1024 + col * 64 + (((0 + quad) ^ (col & 7)) << 3)];
        short8 ap1 = *(const short8*)&PsN[w * 1024 + col * 64 + (((4 + quad) ^ (col & 7)) << 3)];
#pragma unroll
        for (int dt = 0; dt < 8; ++dt) {
          const int rv = dt * 16 + col;
          short8 vf0 = *(const short8*)&Vs[buf * 8192 + rv * 64 + (((0 + quad) ^ (rv & 7)) << 3)];
          acc[dt] = __builtin_amdgcn_mfma_f32_16x16x32_bf16(ap0, vf0, acc[dt], 0, 0, 0);
          short8 vf1 = *(const short8*)&Vs[buf * 8192 + rv * 64 + (((4 + quad) ^ (rv & 7)) << 3)];
          acc[dt] = __builtin_amdgcn_mfma_f32_16x16x32_bf16(ap1, vf1, acc[dt], 0, 0, 0);
        }
      };

      if (common) {
        do_pass(2, lC, accC);
      } else {
        if (selAny) do_pass(0, lS, accS);
        if (winAny) do_pass(1, lW, accW);
      }
    }
    cur = nxt;
    buf ^= 1;
  }

  // epilogue: merge common stream; cmp contribution straight from registers (f32, no bf16 bounce)
#pragma unroll
  for (int r = 0; r < 4; ++r) {
    float a = lS[r] + lC[r];
    a += __shfl_xor(a, 1); a += __shfl_xor(a, 2); a += __shfl_xor(a, 4); a += __shfl_xor(a, 8);
    lS[r] = a;
    float b = lW[r] + lC[r];
    b += __shfl_xor(b, 1); b += __shfl_xor(b, 2); b += __shfl_xor(b, 4); b += __shfl_xor(b, 8);
    lW[r] = b;
  }
  const float g0 = gate[i_lane * 3 + 0];
  const float g1 = gate[i_lane * 3 + 1];
  const float g2 = gate[i_lane * 3 + 2];
#pragma unroll
  for (int r = 0; r < 4; ++r) {
    const size_t base = ((size_t)i_lane * NHQ + h * 4 + r) * DH;
    const float rls = g1 / lS[r];
    const float rlw = g2 / lW[r];
#pragma unroll
    for (int dt = 0; dt < 8; ++dt) {
      const size_t o = base + dt * 16 + col;
      outc[o] = f2bf(g0 * accCmp[dt][r] + rls * (accS[dt][r] + accC[dt][r])
                                        + rlw * (accW[dt][r] + accC[dt][r]));
    }
  }
}

// ---------------- launcher ----------------
extern "C" void kernel_launch(void* const* d_in, const int* in_sizes, int n_in,
                              void* d_out, int out_size, void* d_ws, size_t ws_size,
                              hipStream_t stream) {
  const float* x   = (const float*)d_in[0];
  const float* Wq  = (const float*)d_in[2];
  const float* Wk  = (const float*)d_in[3];
  const float* Wv  = (const float*)d_in[4];
  const float* Wo  = (const float*)d_in[5];
  const float* Wck = (const float*)d_in[6];
  const float* Wcv = (const float*)d_in[7];
  const float* pe  = (const float*)d_in[8];
  const float* Wg  = (const float*)d_in[9];
  float* out = (float*)d_out;

  unsigned char* p = (unsigned char*)d_ws;
  auto alloc = [&](size_t bytes) { void* r = p; p += (bytes + 255) & ~(size_t)255; return r; };
  float* gbuf = (float*)alloc((size_t)SEQ * 4 * 4);
  unsigned short* ckbf = (unsigned short*)alloc((size_t)128 * NHKV * DH * 2);
  unsigned short* cvbf = (unsigned short*)alloc((size_t)128 * NHKV * DH * 2);
  unsigned short* xbf  = (unsigned short*)alloc((size_t)SEQ * HID * 2);        // 8MB; -> Ak/Av
  unsigned short* WqkvT = (unsigned short*)alloc((size_t)NQKV * HID * 2);      // 12MB; -> Cpart -> combbf
  unsigned short* WckT = (unsigned short*)alloc((size_t)NHKV * DH * CKD * 2);  // 4MB
  unsigned short* WcvT = (unsigned short*)alloc((size_t)NHKV * DH * CKD * 2);  // 4MB
  unsigned short* qbf  = (unsigned short*)alloc((size_t)SEQ * NHQ * DH * 2);   // 8MB
  unsigned short* krbf = (unsigned short*)alloc((size_t)SEQ * NHKV * DH * 2);  // 2MB
  float*          knrf = (float*)alloc((size_t)SEQ * NHKV * DH * 4);           // 4MB (raw k f32)
  unsigned short* vbf  = (unsigned short*)alloc((size_t)SEQ * NHKV * DH * 2);  // 2MB
  unsigned short* vT   = (unsigned short*)alloc((size_t)NHKV * DH * SEQ * 2);  // 2MB
  unsigned short* WoT  = (unsigned short*)alloc((size_t)NHQ * DH * HID * 2);   // 8MB (dedicated)
  unsigned short* Ak     = xbf;                                   // overlay xbf (dead after qkv GEMM)
  unsigned short* Av     = xbf + (size_t)NHKV * 128 * CKD;
  float* Cpart = (float*)WqkvT;                                   // 8MB overlay (weights dead after GEMM)
  unsigned short* combbf = WqkvT;                                 // overlay after Cpart dead

  // merged prep: gate+x->bf16 | Wq/Wk/Wv transpose | Wck/Wcv transpose | Wo transpose
  prep_kernel<<<15360, 256, 0, stream>>>(x, Wg, Wq, Wk, Wv, Wo, Wck, Wcv,
                                         gbuf, xbf, WqkvT, WckT, WcvT, WoT);
  // qkv projection with fused RoPE/V-transpose epilogue (no f32 qkv intermediate)
  qkv_gemm_fused<<<dim3(NQKV / 128, SEQ / 64), 256, 0, stream>>>(xbf, WqkvT, qbf, krbf, knrf, vbf, vT);
  // compression as GEMM (A-build over dead xbf; Cpart overlays dead WqkvT weights)
  abuild_kernel<<<(NHKV * 128 * CKD) / 256, 256, 0, stream>>>(knrf, vbf, pe, Ak, Av);
  compress_gemm<<<128, 256, 0, stream>>>(Ak, Av, WckT, WcvT, Cpart);
  compress_reduce_rope<<<(32768 + 65536) / 256, 256, 0, stream>>>(Cpart, ckbf, cvbf);
  // fused compressed-attn + top-k + selected/window attn + gated combine
  fused_attn_kernel<<<(SEQ / 16) * NHKV, 256, 0, stream>>>(qbf, ckbf, cvbf, krbf, vT, gbuf, combbf);
  // output projection (BM=64, BK=64 tile: 512 blocks = 2 blocks/CU)
  gemm_bf16_64<<<dim3(HID / 128, SEQ / 64), 256, 0, stream>>>(combbf, WoT, out, SEQ, HID, NHQ * DH);
}